// Round 1
// baseline (549.051 us; speedup 1.0000x reference)
//
#include <hip/hip_runtime.h>

typedef __attribute__((ext_vector_type(8))) __bf16 bf16x8;
typedef __attribute__((ext_vector_type(4))) float f32x4;
typedef unsigned short u16;

#define MFMA16(a,b,c) __builtin_amdgcn_mfma_f32_16x16x32_bf16(a,b,c,0,0,0)

// ---------------- workspace layout (bytes) ----------------
// wqkv : __bf16[110592] @ 0        [ct0..35][ks0..5][lane][j]   (221184 B)
// wproj: __bf16[36864]  @ 221184   [ct0..11][ks0..5][lane][j]   (73728 B)
// biasf: float [24576]  @ 294912   [h][mt][nt][lane][r]         (98304 B)
// maskf: float [262144] @ 393216   [w][mt][nt][lane][r]         (1048576 B)
// total 1441792 B
#define NWQKV  110592
#define NWPROJ 36864
#define NBIAS  24576
#define NMASK  262144

__global__ void prep_kernel(const float* __restrict__ qkv_w,
                            const float* __restrict__ proj_w,
                            const float* __restrict__ bias_table,
                            const int*   __restrict__ rel_index,
                            const float* __restrict__ mask,
                            __bf16* __restrict__ wqkv,
                            __bf16* __restrict__ wproj,
                            float* __restrict__ biasf,
                            float* __restrict__ maskf)
{
    int idx = blockIdx.x * 256 + threadIdx.x;
    if (idx < NWQKV) {
        int ct = idx / 3072; int rem = idx - ct * 3072;
        int ks = rem >> 9; int lane = (rem >> 3) & 63; int j = rem & 7;
        int o  = ct * 16 + (lane & 15);
        int kk = ks * 32 + (lane >> 4) * 8 + j;
        wqkv[idx] = (__bf16)qkv_w[o * 192 + kk];
        return;
    }
    idx -= NWQKV;
    if (idx < NWPROJ) {
        int ct = idx / 3072; int rem = idx - ct * 3072;
        int ks = rem >> 9; int lane = (rem >> 3) & 63; int j = rem & 7;
        int o  = ct * 16 + (lane & 15);
        int kk = ks * 32 + (lane >> 4) * 8 + j;
        wproj[idx] = (__bf16)proj_w[o * 192 + kk];
        return;
    }
    idx -= NWPROJ;
    if (idx < NBIAS) {
        int h = idx >> 12; int rem = idx & 4095;
        int mt = (rem >> 10) & 3, nt = (rem >> 8) & 3;
        int lane = (rem >> 2) & 63, r = rem & 3;
        int m  = mt * 16 + (lane >> 4) * 4 + r;   // query row
        int nn = nt * 16 + (lane & 15);           // key col
        float v;
        if (nn >= 49)      v = -1e30f;            // mask out padded keys
        else if (m >= 49)  v = 0.f;
        else               v = bias_table[rel_index[m * 49 + nn] * 6 + h];
        biasf[idx] = v;
        return;
    }
    idx -= NBIAS;
    if (idx < NMASK) {
        int w = idx >> 12; int rem = idx & 4095;
        int mt = (rem >> 10) & 3, nt = (rem >> 8) & 3;
        int lane = (rem >> 2) & 63, r = rem & 3;
        int m  = mt * 16 + (lane >> 4) * 4 + r;
        int nn = nt * 16 + (lane & 15);
        maskf[idx] = (m < 49 && nn < 49) ? mask[(w * 49 + m) * 49 + nn] : 0.f;
    }
}

// One block = one window. 384 threads = 6 waves = 6 heads.
// LDS (96 KB):
//   s_qkp[6*4096] : per head: q [4 cb_d][64 tok][8] (2048) + k same (2048).
//                   After QK^T, head h's wave overlays P [8 cb_key][64 qtok][8].
//   s_vT [6*2048] : per head: vT [8 cb_tok][32 d][8]
//   s_xb [12288]  : x bf16 [24 cb_k][64 row][8]; reused as attn_out after phase 1.
__global__ __launch_bounds__(384, 1)
void win_attn_kernel(const float* __restrict__ x,
                     const float* __restrict__ qkv_b,
                     const float* __restrict__ proj_b,
                     const __bf16* __restrict__ wqkv,
                     const __bf16* __restrict__ wproj,
                     const float* __restrict__ biasf,
                     const float* __restrict__ maskf,
                     float* __restrict__ out)
{
    __shared__ __bf16 s_qkp[6 * 4096];
    __shared__ __bf16 s_vT[6 * 2048];
    __shared__ __bf16 s_xb[12288];

    const int b    = blockIdx.x;
    const int tid  = threadIdx.x;
    const int wv   = tid >> 6;     // wave 0..5
    const int lane = tid & 63;
    const int g    = lane >> 4;    // 0..3
    const int ln   = lane & 15;

    const f32x4 fzero = {0.f, 0.f, 0.f, 0.f};

    // ---------------- phase 0: stage x -> bf16 LDS ----------------
    const float* xg = x + (size_t)b * 9408;   // 49*192
    #pragma unroll
    for (int it = 0; it < 4; ++it) {
        int pair = it * 384 + tid;            // 0..1535
        int row = pair & 63, cb = pair >> 6;  // cb 0..23
        bf16x8 v8;
        if (row < 49) {
            const float* p = xg + row * 192 + cb * 8;
            #pragma unroll
            for (int j = 0; j < 8; ++j) v8[j] = (__bf16)p[j];
        } else {
            #pragma unroll
            for (int j = 0; j < 8; ++j) v8[j] = (__bf16)0.f;
        }
        *reinterpret_cast<bf16x8*>(&s_xb[(cb * 64 + row) * 8]) = v8;
    }
    __syncthreads();

    // ---------------- phase 1: QKV projection ----------------
    {
        f32x4 acc[4][6];
        #pragma unroll
        for (int mt = 0; mt < 4; ++mt)
            #pragma unroll
            for (int i = 0; i < 6; ++i) acc[mt][i] = fzero;

        #pragma unroll
        for (int ks = 0; ks < 6; ++ks) {
            bf16x8 a[4], bb[6];
            #pragma unroll
            for (int mt = 0; mt < 4; ++mt)
                a[mt] = *reinterpret_cast<const bf16x8*>(
                    &s_xb[((ks * 4 + g) * 64 + mt * 16 + ln) * 8]);
            #pragma unroll
            for (int i = 0; i < 6; ++i) {
                int ct = wv * 6 + i;
                bb[i] = *reinterpret_cast<const bf16x8*>(
                    &wqkv[((ct * 6 + ks) * 64 + lane) * 8]);
            }
            #pragma unroll
            for (int i = 0; i < 6; ++i)
                #pragma unroll
                for (int mt = 0; mt < 4; ++mt)
                    acc[mt][i] = MFMA16(a[mt], bb[i], acc[mt][i]);
        }
        // epilogue: +bias, scale q, scatter to per-head LDS layouts
        #pragma unroll
        for (int i = 0; i < 6; ++i) {
            int ct = wv * 6 + i;
            int o  = ct * 16 + ln;
            float bo = qkv_b[o];
            int sec = o / 192;        // 0=q 1=k 2=v (uniform per ct)
            int oo  = o % 192;
            int h = oo >> 5, d = oo & 31;
            #pragma unroll
            for (int mt = 0; mt < 4; ++mt)
                #pragma unroll
                for (int r = 0; r < 4; ++r) {
                    float val = acc[mt][i][r] + bo;
                    int m = mt * 16 + g * 4 + r;     // token
                    if (sec == 0) {
                        val *= 0.17677669529663687f; // 1/sqrt(32)
                        s_qkp[h * 4096 + (d >> 3) * 512 + m * 8 + (d & 7)] = (__bf16)val;
                    } else if (sec == 1) {
                        s_qkp[h * 4096 + 2048 + (d >> 3) * 512 + m * 8 + (d & 7)] = (__bf16)val;
                    } else {
                        s_vT[h * 2048 + (m >> 3) * 256 + d * 8 + (m & 7)] = (__bf16)val;
                    }
                }
        }
    }
    __syncthreads();

    // ---------------- phase 2: attention (wave wv = head wv) ----------------
    float rsum[4][4];
    {
        const int h = wv;
        const int wdw = b & 63;
        const __bf16* qb = &s_qkp[h * 4096];
        const __bf16* kb = qb + 2048;

        bf16x8 qa[4], ka[4];
        #pragma unroll
        for (int mt = 0; mt < 4; ++mt)
            qa[mt] = *reinterpret_cast<const bf16x8*>(&qb[(g * 64 + mt * 16 + ln) * 8]);
        #pragma unroll
        for (int nt = 0; nt < 4; ++nt)
            ka[nt] = *reinterpret_cast<const bf16x8*>(&kb[(g * 64 + nt * 16 + ln) * 8]);

        f32x4 s[4][4];
        #pragma unroll
        for (int mt = 0; mt < 4; ++mt)
            #pragma unroll
            for (int nt = 0; nt < 4; ++nt)
                s[mt][nt] = MFMA16(qa[mt], ka[nt], fzero);

        // + relative-position bias + window mask (fragment-order tables)
        #pragma unroll
        for (int mt = 0; mt < 4; ++mt)
            #pragma unroll
            for (int nt = 0; nt < 4; ++nt) {
                f32x4 bv = *reinterpret_cast<const f32x4*>(
                    &biasf[(((h * 4 + mt) * 4 + nt) * 64 + lane) * 4]);
                f32x4 mv = *reinterpret_cast<const f32x4*>(
                    &maskf[(((wdw * 4 + mt) * 4 + nt) * 64 + lane) * 4]);
                #pragma unroll
                for (int r = 0; r < 4; ++r) s[mt][nt][r] += bv[r] + mv[r];
            }

        // register softmax over key dim (64 cols, padded keys are -1e30)
        #pragma unroll
        for (int mt = 0; mt < 4; ++mt)
            #pragma unroll
            for (int r = 0; r < 4; ++r) {
                float mx = s[mt][0][r];
                #pragma unroll
                for (int nt = 1; nt < 4; ++nt) mx = fmaxf(mx, s[mt][nt][r]);
                #pragma unroll
                for (int off = 1; off < 16; off <<= 1)
                    mx = fmaxf(mx, __shfl_xor(mx, off, 64));
                float sum = 0.f;
                #pragma unroll
                for (int nt = 0; nt < 4; ++nt) {
                    float p = __expf(s[mt][nt][r] - mx);
                    s[mt][nt][r] = p;
                    sum += p;
                }
                #pragma unroll
                for (int off = 1; off < 16; off <<= 1)
                    sum += __shfl_xor(sum, off, 64);
                rsum[mt][r] = sum;
            }

        // write unnormalized P, overlaying this head's (dead) q+k region
        __bf16* pb = &s_qkp[h * 4096];
        #pragma unroll
        for (int mt = 0; mt < 4; ++mt)
            #pragma unroll
            for (int nt = 0; nt < 4; ++nt)
                #pragma unroll
                for (int r = 0; r < 4; ++r) {
                    int m  = mt * 16 + g * 4 + r;
                    int nn = nt * 16 + ln;
                    pb[(nn >> 3) * 512 + m * 8 + (nn & 7)] = (__bf16)s[mt][nt][r];
                }

        // PV
        const __bf16* vb = &s_vT[h * 2048];
        f32x4 oacc[4][2];
        #pragma unroll
        for (int mt = 0; mt < 4; ++mt)
            #pragma unroll
            for (int nt = 0; nt < 2; ++nt) oacc[mt][nt] = fzero;
        #pragma unroll
        for (int ks = 0; ks < 2; ++ks) {
            bf16x8 pa[4], vf[2];
            #pragma unroll
            for (int mt = 0; mt < 4; ++mt)
                pa[mt] = *reinterpret_cast<const bf16x8*>(
                    &pb[((ks * 4 + g) * 64 + mt * 16 + ln) * 8]);
            #pragma unroll
            for (int nt = 0; nt < 2; ++nt)
                vf[nt] = *reinterpret_cast<const bf16x8*>(
                    &vb[((ks * 4 + g) * 32 + nt * 16 + ln) * 8]);
            #pragma unroll
            for (int mt = 0; mt < 4; ++mt)
                #pragma unroll
                for (int nt = 0; nt < 2; ++nt)
                    oacc[mt][nt] = MFMA16(pa[mt], vf[nt], oacc[mt][nt]);
        }

        // normalize + write attn_out into s_xb (x is dead)
        #pragma unroll
        for (int mt = 0; mt < 4; ++mt)
            #pragma unroll
            for (int nt = 0; nt < 2; ++nt)
                #pragma unroll
                for (int r = 0; r < 4; ++r) {
                    int m   = mt * 16 + g * 4 + r;
                    int col = h * 32 + nt * 16 + ln;
                    float val = oacc[mt][nt][r] / rsum[mt][r];
                    s_xb[(col >> 3) * 512 + m * 8 + (col & 7)] = (__bf16)val;
                }
    }
    __syncthreads();

    // ---------------- phase 3: output projection ----------------
    {
        f32x4 acc[4][2];
        #pragma unroll
        for (int mt = 0; mt < 4; ++mt)
            #pragma unroll
            for (int i = 0; i < 2; ++i) acc[mt][i] = fzero;

        #pragma unroll
        for (int ks = 0; ks < 6; ++ks) {
            bf16x8 a[4], bb[2];
            #pragma unroll
            for (int mt = 0; mt < 4; ++mt)
                a[mt] = *reinterpret_cast<const bf16x8*>(
                    &s_xb[((ks * 4 + g) * 64 + mt * 16 + ln) * 8]);
            #pragma unroll
            for (int i = 0; i < 2; ++i) {
                int ct = wv * 2 + i;
                bb[i] = *reinterpret_cast<const bf16x8*>(
                    &wproj[((ct * 6 + ks) * 64 + lane) * 8]);
            }
            #pragma unroll
            for (int i = 0; i < 2; ++i)
                #pragma unroll
                for (int mt = 0; mt < 4; ++mt)
                    acc[mt][i] = MFMA16(a[mt], bb[i], acc[mt][i]);
        }
        #pragma unroll
        for (int i = 0; i < 2; ++i) {
            int o = (wv * 2 + i) * 16 + ln;
            float pbv = proj_b[o];
            #pragma unroll
            for (int mt = 0; mt < 4; ++mt)
                #pragma unroll
                for (int r = 0; r < 4; ++r) {
                    int m = mt * 16 + g * 4 + r;
                    if (m < 49)
                        out[((size_t)b * 49 + m) * 192 + o] = acc[mt][i][r] + pbv;
                }
        }
    }
}

extern "C" void kernel_launch(void* const* d_in, const int* in_sizes, int n_in,
                              void* d_out, int out_size, void* d_ws, size_t ws_size,
                              hipStream_t stream) {
    const float* x        = (const float*)d_in[0];
    const float* mask     = (const float*)d_in[1];
    const float* qkv_w    = (const float*)d_in[2];
    const float* qkv_b    = (const float*)d_in[3];
    const float* proj_w   = (const float*)d_in[4];
    const float* proj_b   = (const float*)d_in[5];
    const float* bias_tab = (const float*)d_in[6];
    const int*   rel_idx  = (const int*)d_in[7];

    __bf16* wqkv  = (__bf16*)d_ws;
    __bf16* wproj = wqkv + NWQKV;
    float*  biasf = (float*)((char*)d_ws + 294912);
    float*  maskf = (float*)((char*)d_ws + 393216);

    const int total = NWQKV + NWPROJ + NBIAS + NMASK;   // 434176
    prep_kernel<<<(total + 255) / 256, 256, 0, stream>>>(
        qkv_w, proj_w, bias_tab, rel_idx, mask, wqkv, wproj, biasf, maskf);

    win_attn_kernel<<<4096, 384, 0, stream>>>(
        x, qkv_b, proj_b, wqkv, wproj, biasf, maskf, (float*)d_out);
}